// Round 6
// baseline (156.136 us; speedup 1.0000x reference)
//
#include <hip/hip_runtime.h>

// CuriosityEngine: the goal_sampler path (32x replicated bottleneck + argmax)
// is output-invariant — all 32 action slices are bit-identical, so
// argmax(predicted_entropy) == 0 always. Only the surprise head matters:
//   surprise = relu(mean_T(x).reshape(B,2D) @ W1 + b1) @ W2 + b2   -> (B,)
//   best_action_idx = 0                                            -> scalar
//
// x: (B=4, T=2048, D=768, 2) fp32 => rows of R=1536 floats, reduce over T.
//
// R5 post-mortem: 196K fp32 atomicAdds into 64 cache lines serialized at the
// atomic unit (~50 µs; kernel sat at 5% HBM / 1.3% VALU). This version keeps
// the single-kernel last-block-election shape but uses plain coalesced stores
// for the hidden partials (768 KB, zero contention) + ONE atomic per block on
// a per-batch counter. Four per-batch finisher blocks reduce in parallel.

#define BB 4
#define TT 2048
#define RR 1536        // 2*D
#define HH 256
#define NJC 24         // j-chunks (1536/64)
#define JCW 64         // j's per chunk (16 float4)
#define NTC 8          // t-chunks (256 rows each)
#define TCH (TT / NTC)
#define NSB (NJC * NTC)   // 192 slices per batch

__global__ __launch_bounds__(256) void curiosity_fused_kernel(
        const float* __restrict__ x,  const float* __restrict__ W1,
        const float* __restrict__ b1, const float* __restrict__ W2,
        const float* __restrict__ b2,
        float* __restrict__ hpart, unsigned* __restrict__ counters,
        float* __restrict__ out) {
    const int jc  = blockIdx.x;            // 0..NJC-1
    const int tc  = blockIdx.y;            // 0..NTC-1
    const int b   = blockIdx.z;
    const int tid = threadIdx.x;

    __shared__ float4 red4[16][16];        // [rowgrp][col_local]
    __shared__ float  sfl[JCW];            // mean-scaled j-slice
    __shared__ int    last_b;              // elected batch, or -1

    // ---- Phase A: reduce 256 rows of this block's 64-col slice of x ----
    const int rowl  = tid >> 4;            // 0..15
    const int colf4 = tid & 15;            // 0..15
    const float4* xb = (const float4*)(x + (size_t)b * TT * RR);
    const int t0  = tc * TCH;
    const int col = jc * 16 + colf4;
    float4 acc = make_float4(0.f, 0.f, 0.f, 0.f);
    #pragma unroll
    for (int pass = 0; pass < 16; ++pass) {
        const int t = t0 + pass * 16 + rowl;
        float4 v = xb[(size_t)t * (RR / 4) + col];
        acc.x += v.x; acc.y += v.y; acc.z += v.z; acc.w += v.w;
    }
    red4[rowl][colf4] = acc;
    __syncthreads();
    if (tid < 16) {
        float4 s = make_float4(0.f, 0.f, 0.f, 0.f);
        #pragma unroll
        for (int r = 0; r < 16; ++r) {
            float4 v = red4[r][tid];
            s.x += v.x; s.y += v.y; s.z += v.z; s.w += v.w;
        }
        const float inv_t = 1.0f / (float)TT;
        sfl[tid * 4 + 0] = s.x * inv_t;
        sfl[tid * 4 + 1] = s.y * inv_t;
        sfl[tid * 4 + 2] = s.z * inv_t;
        sfl[tid * 4 + 3] = s.w * inv_t;
    }
    __syncthreads();

    // ---- Phase B: GEMV slice, thread == h; W1 coalesced, sfl broadcast ----
    const int jbase = jc * JCW;
    float hacc = 0.f;
    #pragma unroll 8
    for (int j = 0; j < JCW; ++j) {
        hacc += sfl[j] * W1[(size_t)(jbase + j) * HH + tid];
    }
    // Plain coalesced store — zero contention.
    const int s_idx = jc * NTC + tc;
    hpart[((size_t)b * NSB + s_idx) * HH + tid] = hacc;

    // ---- Phase C: per-batch election (one atomic per BLOCK) ----
    __threadfence();                       // release: L2 writeback, cross-XCD
    if (tid == 0) {
        unsigned old = atomicAdd(&counters[b], 1u);
        last_b = (old == NSB - 1) ? b : -1;
    }
    __syncthreads();
    if (last_b < 0) return;
    const int bb = last_b;
    __threadfence();                       // acquire: invalidate stale lines

    // ---- Phase D (one finisher block per batch, 4 run in parallel) ----
    const float* hp = hpart + (size_t)bb * NSB * HH;
    float a0 = 0.f, a1 = 0.f, a2 = 0.f, a3 = 0.f;
    #pragma unroll 4
    for (int s = 0; s < NSB; s += 4) {     // 4 independent chains, coalesced
        a0 += hp[(size_t)(s + 0) * HH + tid];
        a1 += hp[(size_t)(s + 1) * HH + tid];
        a2 += hp[(size_t)(s + 2) * HH + tid];
        a3 += hp[(size_t)(s + 3) * HH + tid];
    }
    float hsum = ((a0 + a1) + (a2 + a3)) + b1[tid];
    float v = fmaxf(hsum, 0.f) * W2[tid];
    #pragma unroll
    for (int off = 32; off > 0; off >>= 1) v += __shfl_down(v, off, 64);
    __shared__ float red[4];
    const int lane = tid & 63, wave = tid >> 6;
    if (lane == 0) red[wave] = v;
    __syncthreads();
    if (tid == 0) {
        out[bb] = red[0] + red[1] + red[2] + red[3] + b2[0];
        if (bb == 0) {
            // best_action_idx: argmax over 32 bit-identical entropies == 0.
            // 0x00000000 is valid under either f32 or i32 readback.
            out[BB] = 0.0f;
        }
    }
}

extern "C" void kernel_launch(void* const* d_in, const int* in_sizes, int n_in,
                              void* d_out, int out_size, void* d_ws, size_t ws_size,
                              hipStream_t stream) {
    const float* x  = (const float*)d_in[0];
    const float* W1 = (const float*)d_in[1];
    const float* b1 = (const float*)d_in[2];
    const float* W2 = (const float*)d_in[3];
    const float* b2 = (const float*)d_in[4];
    // d_in[5..8] (Wd, bd, Wu, bu) unused: bottleneck path is output-invariant.

    float*    hpart    = (float*)d_ws;                 // BB*NSB*HH fp32 (~768 KB)
    unsigned* counters = (unsigned*)(hpart + (size_t)BB * NSB * HH);

    // Zero only the 4 per-batch counters (ws is 0xAA-poisoned each launch).
    hipMemsetAsync(counters, 0, BB * sizeof(unsigned), stream);

    curiosity_fused_kernel<<<dim3(NJC, NTC, BB), 256, 0, stream>>>(
        x, W1, b1, W2, b2, hpart, counters, (float*)d_out);
}

// Round 7
// 120.509 us; speedup vs baseline: 1.2956x; 1.2956x over previous
//
#include <hip/hip_runtime.h>

// CuriosityEngine: the goal_sampler path (32x replicated bottleneck + argmax)
// is output-invariant — all 32 action slices are bit-identical, so
// argmax(predicted_entropy) == 0 always. Only the surprise head matters:
//   surprise = relu(mean_T(x).reshape(B,2D) @ W1 + b1) @ W2 + b2   -> (B,)
//   best_action_idx = 0                                            -> scalar
//
// x: (B=4, T=2048, D=768, 2) fp32 => rows of R=1536 floats, reduce over T.
//
// R6 post-mortem: the killer was the per-block device-scope __threadfence()
// (agent fences on gfx950 emit buffer_wbl2/buffer_inv — 768 blocks of L2
// writeback storms serialized the whole cache; both pipes idle). This version
// has ZERO fences: all cross-block-visible writes are atomics (coherent at
// the device coherence point by construction):
//   - workers publish hpart slices via atomicExch, consuming the returned old
//     value (forces vmcnt wait => swap COMPLETE before __syncthreads)
//   - one atomicAdd per block elects a per-batch finisher
//   - finishers read slices via atomicAdd(p, 0.0f) (coherence-point reads,
//     immune to stale clean lines in the local XCD L2)

#define BB 4
#define TT 2048
#define RR 1536        // 2*D
#define HH 256
#define NJC 24         // j-chunks (1536/64)
#define JCW 64         // j's per chunk (16 float4)
#define NTC 8          // t-chunks (256 rows each)
#define TCH (TT / NTC)
#define NSB (NJC * NTC)   // 192 slices per batch

__global__ __launch_bounds__(256) void curiosity_fused_kernel(
        const float* __restrict__ x,  const float* __restrict__ W1,
        const float* __restrict__ b1, const float* __restrict__ W2,
        const float* __restrict__ b2,
        float* __restrict__ hpart, unsigned* __restrict__ counters,
        float* __restrict__ out) {
    const int jc  = blockIdx.x;            // 0..NJC-1
    const int tc  = blockIdx.y;            // 0..NTC-1
    const int b   = blockIdx.z;
    const int tid = threadIdx.x;

    __shared__ float4 red4[16][16];        // [rowgrp][col_local]
    __shared__ float  sfl[JCW];            // mean-scaled j-slice
    __shared__ int    last_b;              // elected batch, or -1

    // ---- Phase A: reduce 256 rows of this block's 64-col slice of x ----
    const int rowl  = tid >> 4;            // 0..15
    const int colf4 = tid & 15;            // 0..15
    const float4* xb = (const float4*)(x + (size_t)b * TT * RR);
    const int t0  = tc * TCH;
    const int col = jc * 16 + colf4;
    float4 acc = make_float4(0.f, 0.f, 0.f, 0.f);
    #pragma unroll
    for (int pass = 0; pass < 16; ++pass) {
        const int t = t0 + pass * 16 + rowl;
        float4 v = xb[(size_t)t * (RR / 4) + col];
        acc.x += v.x; acc.y += v.y; acc.z += v.z; acc.w += v.w;
    }
    red4[rowl][colf4] = acc;
    __syncthreads();
    if (tid < 16) {
        float4 s = make_float4(0.f, 0.f, 0.f, 0.f);
        #pragma unroll
        for (int r = 0; r < 16; ++r) {
            float4 v = red4[r][tid];
            s.x += v.x; s.y += v.y; s.z += v.z; s.w += v.w;
        }
        const float inv_t = 1.0f / (float)TT;
        sfl[tid * 4 + 0] = s.x * inv_t;
        sfl[tid * 4 + 1] = s.y * inv_t;
        sfl[tid * 4 + 2] = s.z * inv_t;
        sfl[tid * 4 + 3] = s.w * inv_t;
    }
    __syncthreads();

    // ---- Phase B: GEMV slice, thread == h; W1 coalesced, sfl broadcast ----
    const int jbase = jc * JCW;
    float hacc = 0.f;
    #pragma unroll 8
    for (int j = 0; j < JCW; ++j) {
        hacc += sfl[j] * W1[(size_t)(jbase + j) * HH + tid];
    }

    // ---- Phase C: publish via atomicExch (device-coherent store), then
    // consume the return => vmcnt wait => swap complete before the barrier.
    const int s_idx = jc * NTC + tc;
    float old = atomicExch(&hpart[((size_t)b * NSB + s_idx) * HH + tid], hacc);
    __asm__ volatile("" :: "v"(old));      // keep 'old' live: forces completion
    __syncthreads();                       // all 4 waves' swaps are complete
    if (tid == 0) {
        unsigned prev = atomicAdd(&counters[b], 1u);
        last_b = (prev == NSB - 1) ? b : -1;
    }
    __syncthreads();
    if (last_b < 0) return;
    const int bb = last_b;

    // ---- Phase D (one finisher block per batch, 4 in parallel) ----
    // Coherence-point reads; 8 independent chains to pipeline latency.
    float* hp = hpart + (size_t)bb * NSB * HH;
    float a[8];
    #pragma unroll
    for (int k = 0; k < 8; ++k) a[k] = 0.f;
    #pragma unroll 3
    for (int s = 0; s < NSB; s += 8) {
        #pragma unroll
        for (int k = 0; k < 8; ++k) {
            a[k] += atomicAdd(&hp[(size_t)(s + k) * HH + tid], 0.0f);
        }
    }
    float hsum = ((a[0] + a[1]) + (a[2] + a[3])) +
                 ((a[4] + a[5]) + (a[6] + a[7])) + b1[tid];
    float v = fmaxf(hsum, 0.f) * W2[tid];
    #pragma unroll
    for (int off = 32; off > 0; off >>= 1) v += __shfl_down(v, off, 64);
    __shared__ float red[4];
    const int lane = tid & 63, wave = tid >> 6;
    if (lane == 0) red[wave] = v;
    __syncthreads();
    if (tid == 0) {
        out[bb] = red[0] + red[1] + red[2] + red[3] + b2[0];
        if (bb == 0) {
            // best_action_idx: argmax over 32 bit-identical entropies == 0.
            // 0x00000000 is valid under either f32 or i32 readback.
            out[BB] = 0.0f;
        }
    }
}

extern "C" void kernel_launch(void* const* d_in, const int* in_sizes, int n_in,
                              void* d_out, int out_size, void* d_ws, size_t ws_size,
                              hipStream_t stream) {
    const float* x  = (const float*)d_in[0];
    const float* W1 = (const float*)d_in[1];
    const float* b1 = (const float*)d_in[2];
    const float* W2 = (const float*)d_in[3];
    const float* b2 = (const float*)d_in[4];
    // d_in[5..8] (Wd, bd, Wu, bu) unused: bottleneck path is output-invariant.

    float*    hpart    = (float*)d_ws;                 // BB*NSB*HH fp32 (~768 KB)
    unsigned* counters = (unsigned*)(hpart + (size_t)BB * NSB * HH);

    // Zero only the 4 per-batch counters (ws is 0xAA-poisoned each launch).
    hipMemsetAsync(counters, 0, BB * sizeof(unsigned), stream);

    curiosity_fused_kernel<<<dim3(NJC, NTC, BB), 256, 0, stream>>>(
        x, W1, b1, W2, b2, hpart, counters, (float*)d_out);
}

// Round 8
// 106.256 us; speedup vs baseline: 1.4694x; 1.1341x over previous
//
#include <hip/hip_runtime.h>

// CuriosityEngine: the goal_sampler path (32x replicated bottleneck + argmax)
// is output-invariant — all 32 action slices are bit-identical, so
// argmax(predicted_entropy) == 0 always. Only the surprise head matters:
//   surprise = relu(mean_T(x).reshape(B,2D) @ W1 + b1) @ W2 + b2   -> (B,)
//   best_action_idx = 0                                            -> scalar
//
// x: (B=4, T=2048, D=768, 2) fp32 => rows of R=1536 floats, reduce over T.
//
// R7 post-mortem: 392K atomic RMWs (exch-publish + add0-read) serialized at
// the coherence-point ALU. This version publishes with RELAXED AGENT-scope
// atomic STORES (sc1 write-through: coherent, full BW, no RMW, no fence) and
// the finishers read with RELAXED AGENT-scope atomic LOADS (sc1: bypass
// stale clean lines in the local XCD L2). __syncthreads() drains vmcnt(0)
// per wave before s_barrier, so the one elect-atomic per block is ordered
// after all publishes. Total RMW atomics: 384 (vs R7's 392K).

#define BB 4
#define TT 2048
#define RR 1536        // 2*D
#define HH 256
#define NJC 24         // j-chunks (1536/64)
#define JCW 64         // j's per chunk (16 float4)
#define NTC 4          // t-chunks (512 rows each)
#define TCH (TT / NTC)
#define NSB (NJC * NTC)   // 96 slices per batch

__global__ __launch_bounds__(256) void curiosity_fused_kernel(
        const float* __restrict__ x,  const float* __restrict__ W1,
        const float* __restrict__ b1, const float* __restrict__ W2,
        const float* __restrict__ b2,
        float* __restrict__ hpart, unsigned* __restrict__ counters,
        float* __restrict__ out) {
    const int jc  = blockIdx.x;            // 0..NJC-1
    const int tc  = blockIdx.y;            // 0..NTC-1
    const int b   = blockIdx.z;
    const int tid = threadIdx.x;

    __shared__ float4 red4[16][16];        // [rowgrp][col_local]
    __shared__ float  sfl[JCW];            // mean-scaled j-slice
    __shared__ int    last_b;              // elected batch, or -1

    // ---- Phase A: reduce 512 rows of this block's 64-col slice of x ----
    const int rowl  = tid >> 4;            // 0..15
    const int colf4 = tid & 15;            // 0..15
    const float4* xb = (const float4*)(x + (size_t)b * TT * RR);
    const int t0  = tc * TCH;
    const int col = jc * 16 + colf4;
    float4 acc = make_float4(0.f, 0.f, 0.f, 0.f);
    #pragma unroll 8
    for (int pass = 0; pass < TCH / 16; ++pass) {   // 32 independent loads
        const int t = t0 + pass * 16 + rowl;
        float4 v = xb[(size_t)t * (RR / 4) + col];
        acc.x += v.x; acc.y += v.y; acc.z += v.z; acc.w += v.w;
    }
    red4[rowl][colf4] = acc;
    __syncthreads();
    if (tid < 16) {
        float4 s = make_float4(0.f, 0.f, 0.f, 0.f);
        #pragma unroll
        for (int r = 0; r < 16; ++r) {
            float4 v = red4[r][tid];
            s.x += v.x; s.y += v.y; s.z += v.z; s.w += v.w;
        }
        const float inv_t = 1.0f / (float)TT;
        sfl[tid * 4 + 0] = s.x * inv_t;
        sfl[tid * 4 + 1] = s.y * inv_t;
        sfl[tid * 4 + 2] = s.z * inv_t;
        sfl[tid * 4 + 3] = s.w * inv_t;
    }
    __syncthreads();

    // ---- Phase B: GEMV slice, thread == h; W1 coalesced, sfl broadcast ----
    const int jbase = jc * JCW;
    float hacc = 0.f;
    #pragma unroll 8
    for (int j = 0; j < JCW; ++j) {
        hacc += sfl[j] * W1[(size_t)(jbase + j) * HH + tid];
    }

    // ---- Phase C: publish via agent-scope relaxed atomic STORE (sc1
    // write-through — coherent without fences, no RMW). ----
    const int s_idx = jc * NTC + tc;
    __hip_atomic_store(&hpart[((size_t)b * NSB + s_idx) * HH + tid], hacc,
                       __ATOMIC_RELAXED, __HIP_MEMORY_SCOPE_AGENT);
    __syncthreads();   // drains vmcnt(0) for all 4 waves => stores complete
    if (tid == 0) {
        unsigned prev = atomicAdd(&counters[b], 1u);   // the ONLY RMW
        last_b = (prev == NSB - 1) ? b : -1;
    }
    __syncthreads();
    if (last_b < 0) return;
    const int bb = last_b;

    // ---- Phase D (one finisher block per batch, 4 in parallel) ----
    // Agent-scope relaxed atomic LOADS (u64 = float2): coherence-point reads.
    const unsigned long long* hp2 =
        (const unsigned long long*)(hpart + (size_t)bb * NSB * HH);
    const int c = tid & 127;               // float2 column 0..127
    const int g = tid >> 7;                // 0..1 slice-group
    float a0 = 0.f, a1 = 0.f;
    #pragma unroll 8
    for (int k = 0; k < NSB / 2; ++k) {    // 48 loads, 8 in flight
        const int s = g * (NSB / 2) + k;
        unsigned long long u = __hip_atomic_load(&hp2[(size_t)s * (HH / 2) + c],
                                                 __ATOMIC_RELAXED,
                                                 __HIP_MEMORY_SCOPE_AGENT);
        union { unsigned long long u; float f[2]; } cv; cv.u = u;
        a0 += cv.f[0];
        a1 += cv.f[1];
    }
    __shared__ float part2[2][HH];         // [group][h]
    part2[g][c * 2 + 0] = a0;
    part2[g][c * 2 + 1] = a1;
    __syncthreads();
    float v = 0.f;
    if (tid < 128) {
        const int h0 = tid * 2;
        float h0v = part2[0][h0 + 0] + part2[1][h0 + 0] + b1[h0 + 0];
        float h1v = part2[0][h0 + 1] + part2[1][h0 + 1] + b1[h0 + 1];
        v = fmaxf(h0v, 0.f) * W2[h0 + 0] + fmaxf(h1v, 0.f) * W2[h0 + 1];
    }
    #pragma unroll
    for (int off = 32; off > 0; off >>= 1) v += __shfl_down(v, off, 64);
    __shared__ float red[2];
    const int lane = tid & 63, wave = tid >> 6;
    if (lane == 0 && wave < 2) red[wave] = v;
    __syncthreads();
    if (tid == 0) {
        out[bb] = red[0] + red[1] + b2[0];
        if (bb == 0) {
            // best_action_idx: argmax over 32 bit-identical entropies == 0.
            // 0x00000000 is valid under either f32 or i32 readback.
            out[BB] = 0.0f;
        }
    }
}

extern "C" void kernel_launch(void* const* d_in, const int* in_sizes, int n_in,
                              void* d_out, int out_size, void* d_ws, size_t ws_size,
                              hipStream_t stream) {
    const float* x  = (const float*)d_in[0];
    const float* W1 = (const float*)d_in[1];
    const float* b1 = (const float*)d_in[2];
    const float* W2 = (const float*)d_in[3];
    const float* b2 = (const float*)d_in[4];
    // d_in[5..8] (Wd, bd, Wu, bu) unused: bottleneck path is output-invariant.

    float*    hpart    = (float*)d_ws;                 // BB*NSB*HH fp32 (~384 KB)
    unsigned* counters = (unsigned*)(hpart + (size_t)BB * NSB * HH);

    // Zero only the 4 per-batch counters (ws is 0xAA-poisoned each launch).
    hipMemsetAsync(counters, 0, BB * sizeof(unsigned), stream);

    curiosity_fused_kernel<<<dim3(NJC, NTC, BB), 256, 0, stream>>>(
        x, W1, b1, W2, b2, hpart, counters, (float*)d_out);
}

// Round 9
// 101.099 us; speedup vs baseline: 1.5444x; 1.0510x over previous
//
#include <hip/hip_runtime.h>

// CuriosityEngine: the goal_sampler path (32x replicated bottleneck + argmax)
// is output-invariant — all 32 action slices are bit-identical, so
// argmax(predicted_entropy) == 0 always. Only the surprise head matters:
//   surprise = relu(mean_T(x).reshape(B,2D) @ W1 + b1) @ W2 + b2   -> (B,)
//   best_action_idx = 0                                            -> scalar
//
// x: (B=4, T=2048, D=768, 2) fp32 => rows of R=1536 floats, reduce over T.
//
// R5-R8 post-mortem: every single-kernel cross-block-coherence scheme
// (threadfence: L2-writeback storm, 50 µs; atomic RMW publish: coherence-
// point serialization, 15-40 µs; sc1 store/load + election: works but the
// finisher tail + extra memset eat the saved dispatch) lost to R4's plain
// two-dispatch structure. Kernel-boundary release/acquire is the cheap,
// correct cross-XCD mechanism. This version = R4 structure + halved
// intermediate traffic (NTC 8->4) + shallower head (24-deep chains).

#define BB 4
#define TT 2048
#define RR 1536        // 2*D
#define HH 256
#define NJC 24         // j-chunks (1536/64)
#define JCW 64         // j's per chunk (16 float4)
#define NTC 4          // t-chunks (512 rows each)
#define TCH (TT / NTC)
#define NSB (NJC * NTC)   // 96 hpart slices per batch

// ---- Kernel 1: per (jc, tc, b): reduce 512 rows of a 64-col slice of x,
// then GEMV that 64-vector against W1[jc-slice] -> hpart. 384 blocks. ----
__global__ __launch_bounds__(256) void fused_colsum_gemv_kernel(
        const float* __restrict__ x, const float* __restrict__ W1,
        float* __restrict__ hpart) {
    const int jc  = blockIdx.x;            // 0..NJC-1
    const int tc  = blockIdx.y;            // 0..NTC-1
    const int b   = blockIdx.z;
    const int tid = threadIdx.x;

    __shared__ float4 red4[16][16];        // [rowgrp][col_local]
    __shared__ float  sfl[JCW];            // mean-scaled j-slice

    // Phase A: reduce this block's 512-row x 64-col slice of x.
    const int rowl  = tid >> 4;            // 0..15
    const int colf4 = tid & 15;            // 0..15
    const float4* xb = (const float4*)(x + (size_t)b * TT * RR);
    const int t0  = tc * TCH;
    const int col = jc * 16 + colf4;
    float4 acc = make_float4(0.f, 0.f, 0.f, 0.f);
    #pragma unroll 8
    for (int pass = 0; pass < TCH / 16; ++pass) {   // 32 independent loads
        const int t = t0 + pass * 16 + rowl;
        float4 v = xb[(size_t)t * (RR / 4) + col];
        acc.x += v.x; acc.y += v.y; acc.z += v.z; acc.w += v.w;
    }
    red4[rowl][colf4] = acc;
    __syncthreads();
    if (tid < 16) {
        float4 s = make_float4(0.f, 0.f, 0.f, 0.f);
        #pragma unroll
        for (int r = 0; r < 16; ++r) {
            float4 v = red4[r][tid];
            s.x += v.x; s.y += v.y; s.z += v.z; s.w += v.w;
        }
        const float inv_t = 1.0f / (float)TT;
        sfl[tid * 4 + 0] = s.x * inv_t;
        sfl[tid * 4 + 1] = s.y * inv_t;
        sfl[tid * 4 + 2] = s.z * inv_t;
        sfl[tid * 4 + 3] = s.w * inv_t;
    }
    __syncthreads();

    // Phase B: GEMV slice, thread == h; W1 coalesced, sfl LDS broadcast.
    const int jbase = jc * JCW;
    float hacc = 0.f;
    #pragma unroll 8
    for (int j = 0; j < JCW; ++j) {
        hacc += sfl[j] * W1[(size_t)(jbase + j) * HH + tid];
    }
    const int s_idx = jc * NTC + tc;
    hpart[((size_t)b * NSB + s_idx) * HH + tid] = hacc;   // plain, coalesced
}

// ---- Kernel 2: sum 96 hpart slices (4-way split), + b1, relu, dot W2,
// write out. 4 blocks x 1024 threads; 24-deep coalesced chains. ----
__global__ __launch_bounds__(1024) void head_kernel(
        const float* __restrict__ hpart, const float* __restrict__ b1,
        const float* __restrict__ W2, const float* __restrict__ b2,
        float* __restrict__ out) {
    const int b   = blockIdx.x;
    const int tid = threadIdx.x;
    const int h   = tid & (HH - 1);
    const int g   = tid >> 8;              // 0..3 s-group

    __shared__ float partial[4][HH];
    __shared__ float red[4];

    const float* hp = hpart + (size_t)b * NSB * HH;
    float a0 = 0.f, a1 = 0.f;
    #pragma unroll 12
    for (int k = 0; k < NSB / 4; k += 2) { // 24 loads, 2 chains
        const int s = g * (NSB / 4) + k;
        a0 += hp[(size_t)(s + 0) * HH + h];
        a1 += hp[(size_t)(s + 1) * HH + h];
    }
    partial[g][h] = a0 + a1;
    __syncthreads();

    float v = 0.f;
    if (tid < HH) {
        float hsum = partial[0][tid] + partial[1][tid] +
                     partial[2][tid] + partial[3][tid] + b1[tid];
        v = fmaxf(hsum, 0.f) * W2[tid];
    }
    #pragma unroll
    for (int off = 32; off > 0; off >>= 1) v += __shfl_down(v, off, 64);
    const int lane = tid & 63, wave = tid >> 6;
    if (lane == 0 && wave < 4) red[wave] = v;
    __syncthreads();
    if (tid == 0) {
        out[b] = red[0] + red[1] + red[2] + red[3] + b2[0];
        if (b == 0) {
            // best_action_idx: argmax over 32 bit-identical entropies == 0.
            // 0x00000000 is valid under either f32 or i32 readback.
            out[BB] = 0.0f;
        }
    }
}

extern "C" void kernel_launch(void* const* d_in, const int* in_sizes, int n_in,
                              void* d_out, int out_size, void* d_ws, size_t ws_size,
                              hipStream_t stream) {
    const float* x  = (const float*)d_in[0];
    const float* W1 = (const float*)d_in[1];
    const float* b1 = (const float*)d_in[2];
    const float* W2 = (const float*)d_in[3];
    const float* b2 = (const float*)d_in[4];
    // d_in[5..8] (Wd, bd, Wu, bu) unused: bottleneck path is output-invariant.

    float* hpart = (float*)d_ws;   // BB*NSB*HH fp32 (~384 KB)

    fused_colsum_gemv_kernel<<<dim3(NJC, NTC, BB), 256, 0, stream>>>(x, W1, hpart);
    head_kernel<<<dim3(BB), 1024, 0, stream>>>(hpart, b1, W2, b2, (float*)d_out);
}